// Round 7
// baseline (97.029 us; speedup 1.0000x reference)
//
#include <hip/hip_runtime.h>
#include <hip/hip_cooperative_groups.h>
#include <math.h>

namespace cg = cooperative_groups;

#define BLOCK 256
#define NWAVE 4        // waves per block
#define WCHUNK 64      // gaussians per wave-chunk
#define MAXGRID 4096
#define RBLOCKS 1024   // fallback path
#define CHUNK 256      // fallback path

typedef float f32x4 __attribute__((ext_vector_type(4)));

// ===========================================================================
// Fused cooperative kernel, wave-independent phase C.
//  A: grid-stride sum q^2 -> partials[gridDim.x]   (one __syncthreads)
//  grid.sync()
//  B: per-wave redundant reduction of partials -> inv_norm (no sync)
//  C: per-WAVE chunks of 64 gaussians; private LDS slice per wave;
//     wave-synchronous staging; NO block syncs -> waves pipeline freely.
// ===========================================================================
__global__ __launch_bounds__(BLOCK) void gp_fused(
    const float4* __restrict__ q,
    const float* __restrict__ scales,
    const float* __restrict__ opac_in,
    double* __restrict__ partials,
    float* __restrict__ cov,
    float* __restrict__ inv_cov,
    float* __restrict__ opac_out,
    int n) {
    __shared__ float s_mat[NWAVE][WCHUNK * 18];  // per wave: [0..576) cov, [576..1152) inv
    __shared__ float s_sc[NWAVE][WCHUNK * 3];
    __shared__ double s_red[NWAVE];

    const int tid = threadIdx.x;
    const int lane = tid & 63;
    const int wid = tid >> 6;
    const int nblk = gridDim.x;

    // ---------------- Phase A ----------------
    double acc = 0.0;
    for (int i = blockIdx.x * BLOCK + tid; i < n; i += nblk * BLOCK) {
        float4 v = q[i];
        acc += (double)v.x * v.x + (double)v.y * v.y +
               (double)v.z * v.z + (double)v.w * v.w;
    }
#pragma unroll
    for (int off = 32; off > 0; off >>= 1) acc += __shfl_down(acc, off);
    if (lane == 0) s_red[wid] = acc;
    __syncthreads();
    if (tid == 0)
        partials[blockIdx.x] = s_red[0] + s_red[1] + s_red[2] + s_red[3];

    cg::this_grid().sync();

    // ---------------- Phase B: per-wave, deterministic, identical ----------
    double a2 = 0.0;
    for (int i = lane; i < nblk; i += 64) a2 += partials[i];
#pragma unroll
    for (int off = 32; off > 0; off >>= 1) a2 += __shfl_down(a2, off);
    const double tot = __shfl(a2, 0);
    const float inv_norm = (float)(1.0 / sqrt(tot));

    // ---------------- Phase C: per-wave chunks, no block sync --------------
    const int nchunks = (n + WCHUNK - 1) / WCHUNK;
    const int gwaves = nblk * NWAVE;
    for (int c = blockIdx.x * NWAVE + wid; c < nchunks; c += gwaves) {
        const int g0 = c * WCHUNK;
        const int count = min(WCHUNK, n - g0);

        // stage scales (coalesced float4) into this wave's LDS slice
        const int nsf = count * 3;   // <=192
        const int nsf4 = nsf >> 2;   // <=48
        const f32x4* sc4 = (const f32x4*)(scales + (size_t)g0 * 3);
        if (lane < nsf4) {
            f32x4 v = sc4[lane];
            *(f32x4*)&s_sc[wid][lane << 2] = v;
        }
        {
            int rem = nsf - (nsf4 << 2);
            if (lane < rem)
                s_sc[wid][(nsf4 << 2) + lane] =
                    scales[(size_t)g0 * 3 + (nsf4 << 2) + lane];
        }

        float4 qi = make_float4(0.f, 0.f, 0.f, 0.f);
        float op = 0.f;
        if (lane < count) {
            qi = q[g0 + lane];       // L3-resident from phase A
            op = opac_in[g0 + lane];
        }

        if (lane < count) {
            float w = qi.x * inv_norm;
            float x = qi.y * inv_norm;
            float y = qi.z * inv_norm;
            float z = qi.w * inv_norm;

            float xx = x * x, yy = y * y, zz = z * z;
            float xy = x * y, xz = x * z, yz = y * z;
            float xw = x * w, yw = y * w, zw = z * w;

            float r00 = 1.f - 2.f * (yy + zz);
            float r01 = 2.f * (xy - zw);
            float r02 = 2.f * (xz + yw);
            float r10 = 2.f * (xy + zw);
            float r11 = 1.f - 2.f * (xx + zz);
            float r12 = 2.f * (yz - xw);
            float r20 = 2.f * (xz - yw);
            float r21 = 2.f * (yz + xw);
            float r22 = 1.f - 2.f * (xx + yy);

            // wave-synchronous LDS read (same wave wrote it; DS is in-order)
            float s0 = s_sc[wid][3 * lane + 0];
            float s1 = s_sc[wid][3 * lane + 1];
            float s2 = s_sc[wid][3 * lane + 2];

            float e0 = __expf(2.f * s0), e1 = __expf(2.f * s1),
                  e2 = __expf(2.f * s2);
            float f0 = 1.f / e0, f1 = 1.f / e1, f2 = 1.f / e2;

            float* mc = &s_mat[wid][lane * 9];
            float* mi = &s_mat[wid][WCHUNK * 9 + lane * 9];
            {
                float a0 = r00 * e0, a1 = r01 * e1, a2v = r02 * e2;
                float b0 = r10 * e0, b1 = r11 * e1, b2 = r12 * e2;
                float g0v = r20 * e0, g1 = r21 * e1, g2 = r22 * e2;
                float m00 = a0 * r00 + a1 * r01 + a2v * r02;
                float m01 = a0 * r10 + a1 * r11 + a2v * r12;
                float m02 = a0 * r20 + a1 * r21 + a2v * r22;
                float m11 = b0 * r10 + b1 * r11 + b2 * r12;
                float m12 = b0 * r20 + b1 * r21 + b2 * r22;
                float m22 = g0v * r20 + g1 * r21 + g2 * r22;
                mc[0] = m00; mc[1] = m01; mc[2] = m02;
                mc[3] = m01; mc[4] = m11; mc[5] = m12;
                mc[6] = m02; mc[7] = m12; mc[8] = m22;
            }
            {
                float a0 = r00 * f0, a1 = r01 * f1, a2v = r02 * f2;
                float b0 = r10 * f0, b1 = r11 * f1, b2 = r12 * f2;
                float g0v = r20 * f0, g1 = r21 * f1, g2 = r22 * f2;
                float m00 = a0 * r00 + a1 * r01 + a2v * r02;
                float m01 = a0 * r10 + a1 * r11 + a2v * r12;
                float m02 = a0 * r20 + a1 * r21 + a2v * r22;
                float m11 = b0 * r10 + b1 * r11 + b2 * r12;
                float m12 = b0 * r20 + b1 * r21 + b2 * r22;
                float m22 = g0v * r20 + g1 * r21 + g2 * r22;
                mi[0] = m00; mi[1] = m01; mi[2] = m02;
                mi[3] = m01; mi[4] = m11; mi[5] = m12;
                mi[6] = m02; mi[7] = m12; mi[8] = m22;
            }
            __builtin_nontemporal_store(1.f / (1.f + __expf(-op)),
                                        opac_out + g0 + lane);
        }

        // wave-coalesced NT float4 stores from this wave's LDS slice
        const int nf = count * 9;   // <=576
        const int nf4 = nf >> 2;    // <=144
        f32x4* covo = (f32x4*)(cov + (size_t)g0 * 9);
        f32x4* invo = (f32x4*)(inv_cov + (size_t)g0 * 9);
        const f32x4* mc4 = (const f32x4*)&s_mat[wid][0];
        const f32x4* mi4 = (const f32x4*)&s_mat[wid][WCHUNK * 9];
        for (int j = lane; j < nf4; j += 64) {
            __builtin_nontemporal_store(mc4[j], covo + j);
            __builtin_nontemporal_store(mi4[j], invo + j);
        }
        for (int j = (nf4 << 2) + lane; j < nf; j += 64) {
            cov[(size_t)g0 * 9 + j] = s_mat[wid][j];
            inv_cov[(size_t)g0 * 9 + j] = s_mat[wid][WCHUNK * 9 + j];
        }
    }
}

// ===========================================================================
// Fallback: proven R6 two-kernel path
// ===========================================================================
__global__ __launch_bounds__(BLOCK) void gp_reduce_sq(
    const float4* __restrict__ q4, int n4, double* __restrict__ partials) {
    __shared__ double sdata[BLOCK];
    double acc = 0.0;
    int stride = gridDim.x * blockDim.x;
    for (int i = blockIdx.x * blockDim.x + threadIdx.x; i < n4; i += stride) {
        float4 v = q4[i];
        acc += (double)v.x * v.x + (double)v.y * v.y +
               (double)v.z * v.z + (double)v.w * v.w;
    }
    sdata[threadIdx.x] = acc;
    __syncthreads();
    for (int s = BLOCK / 2; s > 0; s >>= 1) {
        if (threadIdx.x < s) sdata[threadIdx.x] += sdata[threadIdx.x + s];
        __syncthreads();
    }
    if (threadIdx.x == 0) partials[blockIdx.x] = sdata[0];
}

__global__ __launch_bounds__(BLOCK) void gp_main(
    const float4* __restrict__ q,
    const float* __restrict__ scales,
    const float* __restrict__ opac_in,
    const double* __restrict__ partials,
    float* __restrict__ cov,
    float* __restrict__ inv_cov,
    float* __restrict__ opac_out,
    int n) {
    __shared__ union SU {
        double red[4];
        float mat[2 * CHUNK * 9];
    } u;
    __shared__ float s_sc[CHUNK * 3];

    const int tid = threadIdx.x;
    const int c0 = blockIdx.x * CHUNK;
    const int count = min(CHUNK, n - c0);

    float4 qi = make_float4(0.f, 0.f, 0.f, 0.f);
    float op = 0.f;
    if (tid < count) {
        qi = q[c0 + tid];
        op = opac_in[c0 + tid];
    }
    const int nsf = count * 3;
    const int nsf4 = nsf >> 2;
    const float4* sc4 = (const float4*)(scales + (size_t)c0 * 3);
    float4 sv = make_float4(0.f, 0.f, 0.f, 0.f);
    if (tid < nsf4) sv = sc4[tid];

    double acc = 0.0;
#pragma unroll
    for (int k = 0; k < RBLOCKS / 256; ++k) acc += partials[tid + 256 * k];
#pragma unroll
    for (int off = 32; off > 0; off >>= 1) acc += __shfl_down(acc, off);
    if ((tid & 63) == 0) u.red[tid >> 6] = acc;

    if (tid < nsf4) {
        s_sc[4 * tid + 0] = sv.x;
        s_sc[4 * tid + 1] = sv.y;
        s_sc[4 * tid + 2] = sv.z;
        s_sc[4 * tid + 3] = sv.w;
    }
    {
        int r = nsf - (nsf4 << 2);
        if (tid < r) s_sc[(nsf4 << 2) + tid] =
            scales[(size_t)c0 * 3 + (nsf4 << 2) + tid];
    }
    __syncthreads();
    double tot = u.red[0] + u.red[1] + u.red[2] + u.red[3];
    const float inv_norm = (float)(1.0 / sqrt(tot));
    __syncthreads();

    if (tid < count) {
        float w = qi.x * inv_norm;
        float x = qi.y * inv_norm;
        float y = qi.z * inv_norm;
        float z = qi.w * inv_norm;
        float xx = x * x, yy = y * y, zz = z * z;
        float xy = x * y, xz = x * z, yz = y * z;
        float xw = x * w, yw = y * w, zw = z * w;
        float r00 = 1.f - 2.f * (yy + zz);
        float r01 = 2.f * (xy - zw);
        float r02 = 2.f * (xz + yw);
        float r10 = 2.f * (xy + zw);
        float r11 = 1.f - 2.f * (xx + zz);
        float r12 = 2.f * (yz - xw);
        float r20 = 2.f * (xz - yw);
        float r21 = 2.f * (yz + xw);
        float r22 = 1.f - 2.f * (xx + yy);
        float s0 = s_sc[3 * tid + 0];
        float s1 = s_sc[3 * tid + 1];
        float s2 = s_sc[3 * tid + 2];
        float e0 = __expf(2.f * s0), e1 = __expf(2.f * s1), e2 = __expf(2.f * s2);
        float f0 = 1.f / e0, f1 = 1.f / e1, f2 = 1.f / e2;
        float* mc = &u.mat[tid * 9];
        float* mi = &u.mat[CHUNK * 9 + tid * 9];
        {
            float a0 = r00 * e0, a1 = r01 * e1, a2 = r02 * e2;
            float b0 = r10 * e0, b1 = r11 * e1, b2 = r12 * e2;
            float g0 = r20 * e0, g1 = r21 * e1, g2 = r22 * e2;
            float m00 = a0 * r00 + a1 * r01 + a2 * r02;
            float m01 = a0 * r10 + a1 * r11 + a2 * r12;
            float m02 = a0 * r20 + a1 * r21 + a2 * r22;
            float m11 = b0 * r10 + b1 * r11 + b2 * r12;
            float m12 = b0 * r20 + b1 * r21 + b2 * r22;
            float m22 = g0 * r20 + g1 * r21 + g2 * r22;
            mc[0] = m00; mc[1] = m01; mc[2] = m02;
            mc[3] = m01; mc[4] = m11; mc[5] = m12;
            mc[6] = m02; mc[7] = m12; mc[8] = m22;
        }
        {
            float a0 = r00 * f0, a1 = r01 * f1, a2 = r02 * f2;
            float b0 = r10 * f0, b1 = r11 * f1, b2 = r12 * f2;
            float g0 = r20 * f0, g1 = r21 * f1, g2 = r22 * f2;
            float m00 = a0 * r00 + a1 * r01 + a2 * r02;
            float m01 = a0 * r10 + a1 * r11 + a2 * r12;
            float m02 = a0 * r20 + a1 * r21 + a2 * r22;
            float m11 = b0 * r10 + b1 * r11 + b2 * r12;
            float m12 = b0 * r20 + b1 * r21 + b2 * r22;
            float m22 = g0 * r20 + g1 * r21 + g2 * r22;
            mi[0] = m00; mi[1] = m01; mi[2] = m02;
            mi[3] = m01; mi[4] = m11; mi[5] = m12;
            mi[6] = m02; mi[7] = m12; mi[8] = m22;
        }
        opac_out[c0 + tid] = 1.f / (1.f + __expf(-op));
    }
    __syncthreads();

    const int nf = count * 9;
    const int nfv = nf >> 2;
    f32x4* covo = (f32x4*)(cov + (size_t)c0 * 9);
    f32x4* invo = (f32x4*)(inv_cov + (size_t)c0 * 9);
    const f32x4* mc4 = (const f32x4*)u.mat;
    const f32x4* mi4 = (const f32x4*)(u.mat + CHUNK * 9);
    for (int j = tid; j < nfv; j += BLOCK) {
        __builtin_nontemporal_store(mc4[j], covo + j);
        __builtin_nontemporal_store(mi4[j], invo + j);
    }
    for (int j = (nfv << 2) + tid; j < nf; j += BLOCK) {
        cov[(size_t)c0 * 9 + j] = u.mat[j];
        inv_cov[(size_t)c0 * 9 + j] = u.mat[CHUNK * 9 + j];
    }
}

extern "C" void kernel_launch(void* const* d_in, const int* in_sizes, int n_in,
                              void* d_out, int out_size, void* d_ws, size_t ws_size,
                              hipStream_t stream) {
    const float4* q = (const float4*)d_in[0];      // (N,4)
    const float* scales = (const float*)d_in[1];   // (N,3)
    const float* opac = (const float*)d_in[2];     // (N,1)
    int n = in_sizes[0] / 4;

    float* out = (float*)d_out;
    float* cov = out;                        // N*9
    float* inv_cov = out + (size_t)n * 9;    // N*9
    float* opac_out = out + (size_t)n * 18;  // N

    double* partials = (double*)d_ws;

    // Deterministic host-side occupancy sizing (same result every call).
    int occ = 0, num_cu = 0;
    hipError_t qe = hipOccupancyMaxActiveBlocksPerMultiprocessor(
        &occ, gp_fused, BLOCK, 0);
    hipError_t ae = hipDeviceGetAttribute(
        &num_cu, hipDeviceAttributeMultiprocessorCount, 0);

    bool coop_ok = false;
    if (qe == hipSuccess && ae == hipSuccess && occ > 0 && num_cu > 0) {
        long grid_l = (long)occ * num_cu;
        if (grid_l > MAXGRID) grid_l = MAXGRID;
        if ((size_t)grid_l * sizeof(double) > ws_size)
            grid_l = (long)(ws_size / sizeof(double));
        int grid = (int)grid_l;
        if (grid >= 64) {
            void* args[] = {(void*)&q, (void*)&scales, (void*)&opac,
                            (void*)&partials, (void*)&cov, (void*)&inv_cov,
                            (void*)&opac_out, (void*)&n};
            hipError_t le = hipLaunchCooperativeKernel(
                (void*)gp_fused, dim3(grid), dim3(BLOCK), args, 0, stream);
            coop_ok = (le == hipSuccess);
        }
    }

    if (!coop_ok) {
        gp_reduce_sq<<<RBLOCKS, BLOCK, 0, stream>>>(q, n, partials);
        int nblocks = (n + CHUNK - 1) / CHUNK;
        gp_main<<<nblocks, BLOCK, 0, stream>>>(
            q, scales, opac, partials, cov, inv_cov, opac_out, n);
    }
}

// Round 8
// 70.425 us; speedup vs baseline: 1.3778x; 1.3778x over previous
//
#include <hip/hip_runtime.h>
#include <math.h>

#define RBLOCKS 1024
#define BLOCK 256
#define CHUNK 256

typedef float f32x4 __attribute__((ext_vector_type(4)));

// ---------------------------------------------------------------------------
// Pass 1: per-block partial sums of q^2 (double, deterministic) + last-block
// finalize: reduce partials -> inv_norm (single float). Classic fence+atomic
// last-block-done pattern; counter is zeroed by hipMemsetAsync every launch.
// ---------------------------------------------------------------------------
__global__ __launch_bounds__(BLOCK) void gp_pass1(
    const float4* __restrict__ q4, int n,
    double* __restrict__ partials,
    unsigned* __restrict__ counter,
    float* __restrict__ inv_norm) {
    __shared__ double sdata[BLOCK];
    __shared__ bool is_last;

    double acc = 0.0;
    const int stride = gridDim.x * blockDim.x;
    for (int i = blockIdx.x * blockDim.x + threadIdx.x; i < n; i += stride) {
        float4 v = q4[i];
        acc += (double)v.x * v.x + (double)v.y * v.y +
               (double)v.z * v.z + (double)v.w * v.w;
    }
    sdata[threadIdx.x] = acc;
    __syncthreads();
    for (int s = BLOCK / 2; s > 0; s >>= 1) {
        if (threadIdx.x < s) sdata[threadIdx.x] += sdata[threadIdx.x + s];
        __syncthreads();
    }
    if (threadIdx.x == 0) {
        partials[blockIdx.x] = sdata[0];
        __threadfence();  // make partials visible device-wide before ticket
        unsigned old = atomicAdd(counter, 1u);
        is_last = (old == gridDim.x - 1);
    }
    __syncthreads();

    if (is_last) {
        __threadfence();  // acquire: see all blocks' partials
        double a = 0.0;
        for (int i = threadIdx.x; i < gridDim.x; i += BLOCK) a += partials[i];
        sdata[threadIdx.x] = a;
        __syncthreads();
        for (int s = BLOCK / 2; s > 0; s >>= 1) {
            if (threadIdx.x < s) sdata[threadIdx.x] += sdata[threadIdx.x + s];
            __syncthreads();
        }
        if (threadIdx.x == 0)
            *inv_norm = (float)(1.0 / sqrt(sdata[0]));
    }
}

// ---------------------------------------------------------------------------
// Pass 2: per-chunk pointwise cov/inv_cov/sigmoid. inv_norm is a single
// pre-reduced float (uniform broadcast load). LDS-staged outputs streamed
// with coalesced non-temporal float4 stores.
// ---------------------------------------------------------------------------
__global__ __launch_bounds__(BLOCK) void gp_main(
    const float4* __restrict__ q,
    const float* __restrict__ scales,
    const float* __restrict__ opac_in,
    const float* __restrict__ inv_norm_p,
    float* __restrict__ cov,
    float* __restrict__ inv_cov,
    float* __restrict__ opac_out,
    int n) {
    __shared__ float s_mat[2 * CHUNK * 9];  // [0..2304) cov, [2304..4608) inv
    __shared__ float s_sc[CHUNK * 3];

    const int tid = threadIdx.x;
    const int c0 = blockIdx.x * CHUNK;
    const int count = min(CHUNK, n - c0);

    // ---- issue input loads early ----
    float4 qi = make_float4(0.f, 0.f, 0.f, 0.f);
    float op = 0.f;
    if (tid < count) {
        qi = q[c0 + tid];           // L3-resident from pass 1
        op = opac_in[c0 + tid];
    }
    // stage scales via coalesced float4 loads
    const int nsf = count * 3;
    const int nsf4 = nsf >> 2;
    const float4* sc4 = (const float4*)(scales + (size_t)c0 * 3);
    float4 sv = make_float4(0.f, 0.f, 0.f, 0.f);
    if (tid < nsf4) sv = sc4[tid];

    const float inv_norm = *inv_norm_p;  // uniform scalar broadcast

    if (tid < nsf4) {
        s_sc[4 * tid + 0] = sv.x;
        s_sc[4 * tid + 1] = sv.y;
        s_sc[4 * tid + 2] = sv.z;
        s_sc[4 * tid + 3] = sv.w;
    }
    {
        int r = nsf - (nsf4 << 2);
        if (tid < r) s_sc[(nsf4 << 2) + tid] =
            scales[(size_t)c0 * 3 + (nsf4 << 2) + tid];
    }
    __syncthreads();

    // ---- compute ----
    if (tid < count) {
        float w = qi.x * inv_norm;
        float x = qi.y * inv_norm;
        float y = qi.z * inv_norm;
        float z = qi.w * inv_norm;

        float xx = x * x, yy = y * y, zz = z * z;
        float xy = x * y, xz = x * z, yz = y * z;
        float xw = x * w, yw = y * w, zw = z * w;

        float r00 = 1.f - 2.f * (yy + zz);
        float r01 = 2.f * (xy - zw);
        float r02 = 2.f * (xz + yw);
        float r10 = 2.f * (xy + zw);
        float r11 = 1.f - 2.f * (xx + zz);
        float r12 = 2.f * (yz - xw);
        float r20 = 2.f * (xz - yw);
        float r21 = 2.f * (yz + xw);
        float r22 = 1.f - 2.f * (xx + yy);

        float s0 = s_sc[3 * tid + 0];
        float s1 = s_sc[3 * tid + 1];
        float s2 = s_sc[3 * tid + 2];

        float e0 = __expf(2.f * s0), e1 = __expf(2.f * s1), e2 = __expf(2.f * s2);
        float f0 = 1.f / e0, f1 = 1.f / e1, f2 = 1.f / e2;

        float* mc = &s_mat[tid * 9];
        float* mi = &s_mat[CHUNK * 9 + tid * 9];
        {
            float a0 = r00 * e0, a1 = r01 * e1, a2 = r02 * e2;
            float b0 = r10 * e0, b1 = r11 * e1, b2 = r12 * e2;
            float g0 = r20 * e0, g1 = r21 * e1, g2 = r22 * e2;
            float m00 = a0 * r00 + a1 * r01 + a2 * r02;
            float m01 = a0 * r10 + a1 * r11 + a2 * r12;
            float m02 = a0 * r20 + a1 * r21 + a2 * r22;
            float m11 = b0 * r10 + b1 * r11 + b2 * r12;
            float m12 = b0 * r20 + b1 * r21 + b2 * r22;
            float m22 = g0 * r20 + g1 * r21 + g2 * r22;
            mc[0] = m00; mc[1] = m01; mc[2] = m02;
            mc[3] = m01; mc[4] = m11; mc[5] = m12;
            mc[6] = m02; mc[7] = m12; mc[8] = m22;
        }
        {
            float a0 = r00 * f0, a1 = r01 * f1, a2 = r02 * f2;
            float b0 = r10 * f0, b1 = r11 * f1, b2 = r12 * f2;
            float g0 = r20 * f0, g1 = r21 * f1, g2 = r22 * f2;
            float m00 = a0 * r00 + a1 * r01 + a2 * r02;
            float m01 = a0 * r10 + a1 * r11 + a2 * r12;
            float m02 = a0 * r20 + a1 * r21 + a2 * r22;
            float m11 = b0 * r10 + b1 * r11 + b2 * r12;
            float m12 = b0 * r20 + b1 * r21 + b2 * r22;
            float m22 = g0 * r20 + g1 * r21 + g2 * r22;
            mi[0] = m00; mi[1] = m01; mi[2] = m02;
            mi[3] = m01; mi[4] = m11; mi[5] = m12;
            mi[6] = m02; mi[7] = m12; mi[8] = m22;
        }
        // opacity (coalesced NT scalar store)
        __builtin_nontemporal_store(1.f / (1.f + __expf(-op)),
                                    opac_out + c0 + tid);
    }
    __syncthreads();

    // ---- coalesced NON-TEMPORAL float4 stores of cov / inv_cov ----
    const int nf = count * 9;
    const int nfv = nf >> 2;
    f32x4* covo = (f32x4*)(cov + (size_t)c0 * 9);
    f32x4* invo = (f32x4*)(inv_cov + (size_t)c0 * 9);
    const f32x4* mc4 = (const f32x4*)s_mat;
    const f32x4* mi4 = (const f32x4*)(s_mat + CHUNK * 9);
    for (int j = tid; j < nfv; j += BLOCK) {
        __builtin_nontemporal_store(mc4[j], covo + j);
        __builtin_nontemporal_store(mi4[j], invo + j);
    }
    for (int j = (nfv << 2) + tid; j < nf; j += BLOCK) {
        cov[(size_t)c0 * 9 + j] = s_mat[j];
        inv_cov[(size_t)c0 * 9 + j] = s_mat[CHUNK * 9 + j];
    }
}

extern "C" void kernel_launch(void* const* d_in, const int* in_sizes, int n_in,
                              void* d_out, int out_size, void* d_ws, size_t ws_size,
                              hipStream_t stream) {
    const float4* q = (const float4*)d_in[0];      // (N,4)
    const float* scales = (const float*)d_in[1];   // (N,3)
    const float* opac = (const float*)d_in[2];     // (N,1)
    int n = in_sizes[0] / 4;

    float* out = (float*)d_out;
    float* cov = out;                        // N*9
    float* inv_cov = out + (size_t)n * 9;    // N*9
    float* opac_out = out + (size_t)n * 18;  // N

    // ws layout: [0,8) counter | [8,16) inv_norm | [16, 16+RBLOCKS*8) partials
    unsigned* counter = (unsigned*)d_ws;
    float* inv_norm = (float*)((char*)d_ws + 8);
    double* partials = (double*)((char*)d_ws + 16);

    hipMemsetAsync(counter, 0, sizeof(unsigned), stream);

    gp_pass1<<<RBLOCKS, BLOCK, 0, stream>>>(q, n, partials, counter, inv_norm);

    int nblocks = (n + CHUNK - 1) / CHUNK;
    gp_main<<<nblocks, BLOCK, 0, stream>>>(
        q, scales, opac, inv_norm, cov, inv_cov, opac_out, n);
}

// Round 9
// 45.231 us; speedup vs baseline: 2.1452x; 1.5570x over previous
//
#include <hip/hip_runtime.h>
#include <math.h>

#define RBLOCKS 1024
#define BLOCK 256
#define CHUNK 256

typedef float f32x4 __attribute__((ext_vector_type(4)));

// ---------------------------------------------------------------------------
// Pass 1: per-block partial sums of q^2 (double accumulation, deterministic)
// ---------------------------------------------------------------------------
__global__ __launch_bounds__(BLOCK) void gp_reduce_sq(
    const float4* __restrict__ q4, int n4, double* __restrict__ partials) {
    __shared__ double sdata[BLOCK];
    double acc = 0.0;
    int stride = gridDim.x * blockDim.x;
    for (int i = blockIdx.x * blockDim.x + threadIdx.x; i < n4; i += stride) {
        float4 v = q4[i];
        acc += (double)v.x * v.x + (double)v.y * v.y +
               (double)v.z * v.z + (double)v.w * v.w;
    }
    sdata[threadIdx.x] = acc;
    __syncthreads();
    for (int s = BLOCK / 2; s > 0; s >>= 1) {
        if (threadIdx.x < s) sdata[threadIdx.x] += sdata[threadIdx.x + s];
        __syncthreads();
    }
    if (threadIdx.x == 0) partials[blockIdx.x] = sdata[0];
}

// ---------------------------------------------------------------------------
// Compute one gaussian's cov/inv_cov into the LDS staging buffer.
// ---------------------------------------------------------------------------
__device__ __forceinline__ void gp_compute_one(
    int tid, float4 qi, float s0, float s1, float s2, float inv_norm,
    float* __restrict__ s_mat) {
    float w = qi.x * inv_norm;
    float x = qi.y * inv_norm;
    float y = qi.z * inv_norm;
    float z = qi.w * inv_norm;

    float xx = x * x, yy = y * y, zz = z * z;
    float xy = x * y, xz = x * z, yz = y * z;
    float xw = x * w, yw = y * w, zw = z * w;

    float r00 = 1.f - 2.f * (yy + zz);
    float r01 = 2.f * (xy - zw);
    float r02 = 2.f * (xz + yw);
    float r10 = 2.f * (xy + zw);
    float r11 = 1.f - 2.f * (xx + zz);
    float r12 = 2.f * (yz - xw);
    float r20 = 2.f * (xz - yw);
    float r21 = 2.f * (yz + xw);
    float r22 = 1.f - 2.f * (xx + yy);

    float e0 = __expf(2.f * s0), e1 = __expf(2.f * s1), e2 = __expf(2.f * s2);
    float f0 = 1.f / e0, f1 = 1.f / e1, f2 = 1.f / e2;

    float* mc = &s_mat[tid * 9];
    float* mi = &s_mat[CHUNK * 9 + tid * 9];
    {
        float a0 = r00 * e0, a1 = r01 * e1, a2 = r02 * e2;
        float b0 = r10 * e0, b1 = r11 * e1, b2 = r12 * e2;
        float g0 = r20 * e0, g1 = r21 * e1, g2 = r22 * e2;
        float m00 = a0 * r00 + a1 * r01 + a2 * r02;
        float m01 = a0 * r10 + a1 * r11 + a2 * r12;
        float m02 = a0 * r20 + a1 * r21 + a2 * r22;
        float m11 = b0 * r10 + b1 * r11 + b2 * r12;
        float m12 = b0 * r20 + b1 * r21 + b2 * r22;
        float m22 = g0 * r20 + g1 * r21 + g2 * r22;
        mc[0] = m00; mc[1] = m01; mc[2] = m02;
        mc[3] = m01; mc[4] = m11; mc[5] = m12;
        mc[6] = m02; mc[7] = m12; mc[8] = m22;
    }
    {
        float a0 = r00 * f0, a1 = r01 * f1, a2 = r02 * f2;
        float b0 = r10 * f0, b1 = r11 * f1, b2 = r12 * f2;
        float g0 = r20 * f0, g1 = r21 * f1, g2 = r22 * f2;
        float m00 = a0 * r00 + a1 * r01 + a2 * r02;
        float m01 = a0 * r10 + a1 * r11 + a2 * r12;
        float m02 = a0 * r20 + a1 * r21 + a2 * r22;
        float m11 = b0 * r10 + b1 * r11 + b2 * r12;
        float m12 = b0 * r20 + b1 * r21 + b2 * r22;
        float m22 = g0 * r20 + g1 * r21 + g2 * r22;
        mi[0] = m00; mi[1] = m01; mi[2] = m02;
        mi[3] = m01; mi[4] = m11; mi[5] = m12;
        mi[6] = m02; mi[7] = m12; mi[8] = m22;
    }
}

// ---------------------------------------------------------------------------
// Stage scales float4 register -> LDS for one chunk (wave-coalesced layout).
// ---------------------------------------------------------------------------
__device__ __forceinline__ void gp_stage_scales(
    int tid, int count, float4 sv, const float* __restrict__ scales,
    size_t g0, float* __restrict__ s_sc) {
    const int nsf = count * 3;
    const int nsf4 = nsf >> 2;
    if (tid < nsf4) {
        s_sc[4 * tid + 0] = sv.x;
        s_sc[4 * tid + 1] = sv.y;
        s_sc[4 * tid + 2] = sv.z;
        s_sc[4 * tid + 3] = sv.w;
    }
    int r = nsf - (nsf4 << 2);
    if (tid < r) s_sc[(nsf4 << 2) + tid] = scales[g0 * 3 + (nsf4 << 2) + tid];
}

// ---------------------------------------------------------------------------
// NT float4 store of one chunk's staged outputs.
// ---------------------------------------------------------------------------
__device__ __forceinline__ void gp_store_chunk(
    int tid, int count, size_t g0, const float* __restrict__ s_mat,
    float* __restrict__ cov, float* __restrict__ inv_cov) {
    const int nf = count * 9;
    const int nfv = nf >> 2;
    f32x4* covo = (f32x4*)(cov + g0 * 9);
    f32x4* invo = (f32x4*)(inv_cov + g0 * 9);
    const f32x4* mc4 = (const f32x4*)s_mat;
    const f32x4* mi4 = (const f32x4*)(s_mat + CHUNK * 9);
    for (int j = tid; j < nfv; j += BLOCK) {
        __builtin_nontemporal_store(mc4[j], covo + j);
        __builtin_nontemporal_store(mi4[j], invo + j);
    }
    for (int j = (nfv << 2) + tid; j < nf; j += BLOCK) {
        cov[g0 * 9 + j] = s_mat[j];
        inv_cov[g0 * 9 + j] = s_mat[CHUNK * 9 + j];
    }
}

// ---------------------------------------------------------------------------
// Pass 2: TWO adjacent chunks per block, software-pipelined. All global
// inputs for both chunks are loaded into registers up front; chunk B's
// compute overlaps chunk A's NT-store drain. Per-block fixed costs
// (partials reduce — L1-hot — and dispatch) amortize over 2 chunks.
// ---------------------------------------------------------------------------
__global__ __launch_bounds__(BLOCK) void gp_main(
    const float4* __restrict__ q,
    const float* __restrict__ scales,
    const float* __restrict__ opac_in,
    const double* __restrict__ partials,
    float* __restrict__ cov,
    float* __restrict__ inv_cov,
    float* __restrict__ opac_out,
    int n) {
    __shared__ union SU {
        double red[4];
        float mat[2 * CHUNK * 9];  // [0..2304) cov, [2304..4608) inv_cov
    } u;
    __shared__ float s_sc[CHUNK * 3];

    const int tid = threadIdx.x;
    const size_t cA0 = (size_t)blockIdx.x * (2 * CHUNK);
    const size_t cB0 = cA0 + CHUNK;
    const int countA = (int)min((long long)CHUNK, (long long)n - (long long)cA0);
    const int countB = (int)max(0LL,
        min((long long)CHUNK, (long long)n - (long long)cB0));

    // ---- issue ALL global input loads up front ----
    float4 qA = make_float4(0.f, 0.f, 0.f, 0.f);
    float opA = 0.f;
    if (tid < countA) {
        qA = q[cA0 + tid];            // L3-resident from pass 1
        opA = opac_in[cA0 + tid];
    }
    float4 qB = make_float4(0.f, 0.f, 0.f, 0.f);
    float opB = 0.f;
    if (tid < countB) {
        qB = q[cB0 + tid];
        opB = opac_in[cB0 + tid];
    }
    const float4* scA4 = (const float4*)(scales + cA0 * 3);
    const float4* scB4 = (const float4*)(scales + cB0 * 3);
    float4 svA = make_float4(0.f, 0.f, 0.f, 0.f);
    float4 svB = make_float4(0.f, 0.f, 0.f, 0.f);
    if (tid < (countA * 3) >> 2) svA = scA4[tid];
    if (tid < (countB * 3) >> 2) svB = scB4[tid];

    // ---- norm: redundant reduce of 1024 partials (L1-hot, deterministic) --
    double acc = 0.0;
#pragma unroll
    for (int k = 0; k < RBLOCKS / 256; ++k) acc += partials[tid + 256 * k];
#pragma unroll
    for (int off = 32; off > 0; off >>= 1) acc += __shfl_down(acc, off);
    if ((tid & 63) == 0) u.red[tid >> 6] = acc;

    gp_stage_scales(tid, countA, svA, scales, cA0, s_sc);
    __syncthreads();

    const double tot = u.red[0] + u.red[1] + u.red[2] + u.red[3];
    const float inv_norm = (float)(1.0 / sqrt(tot));
    __syncthreads();  // u.red reads done before u.mat overwrites

    // ================= chunk A =================
    if (tid < countA) {
        gp_compute_one(tid, qA, s_sc[3 * tid + 0], s_sc[3 * tid + 1],
                       s_sc[3 * tid + 2], inv_norm, u.mat);
        __builtin_nontemporal_store(1.f / (1.f + __expf(-opA)),
                                    opac_out + cA0 + tid);
    }
    __syncthreads();

    gp_store_chunk(tid, countA, cA0, u.mat, cov, inv_cov);
    // B scales can reuse s_sc: all A reads of s_sc happened before the
    // previous barrier.
    gp_stage_scales(tid, countB, svB, scales, cB0, s_sc);
    __syncthreads();  // A's u.mat reads + B's s_sc writes complete

    // ================= chunk B =================
    if (tid < countB) {
        gp_compute_one(tid, qB, s_sc[3 * tid + 0], s_sc[3 * tid + 1],
                       s_sc[3 * tid + 2], inv_norm, u.mat);
        __builtin_nontemporal_store(1.f / (1.f + __expf(-opB)),
                                    opac_out + cB0 + tid);
    }
    __syncthreads();

    gp_store_chunk(tid, countB, cB0, u.mat, cov, inv_cov);
}

extern "C" void kernel_launch(void* const* d_in, const int* in_sizes, int n_in,
                              void* d_out, int out_size, void* d_ws, size_t ws_size,
                              hipStream_t stream) {
    const float4* q = (const float4*)d_in[0];      // (N,4)
    const float* scales = (const float*)d_in[1];   // (N,3)
    const float* opac = (const float*)d_in[2];     // (N,1)
    int n = in_sizes[0] / 4;

    float* out = (float*)d_out;
    float* cov = out;                        // N*9
    float* inv_cov = out + (size_t)n * 9;    // N*9
    float* opac_out = out + (size_t)n * 18;  // N

    double* partials = (double*)d_ws;        // RBLOCKS doubles

    gp_reduce_sq<<<RBLOCKS, BLOCK, 0, stream>>>(q, n, partials);

    int nblocks = (n + 2 * CHUNK - 1) / (2 * CHUNK);
    gp_main<<<nblocks, BLOCK, 0, stream>>>(
        q, scales, opac, partials, cov, inv_cov, opac_out, n);
}

// Round 10
// 43.713 us; speedup vs baseline: 2.2196x; 1.0347x over previous
//
#include <hip/hip_runtime.h>
#include <math.h>

#define RBLOCKS 1024
#define RTHREADS 256
#define CHUNK 256
#define BLOCK 256

typedef float f32x4 __attribute__((ext_vector_type(4)));

// ---------------------------------------------------------------------------
// Stage 1: per-block partial sums of q^2 (double accumulation, deterministic)
// ---------------------------------------------------------------------------
__global__ __launch_bounds__(RTHREADS) void gp_reduce_sq(
    const float4* __restrict__ q4, int n4, double* __restrict__ partials) {
    __shared__ double sdata[RTHREADS];
    double acc = 0.0;
    int stride = gridDim.x * blockDim.x;
    for (int i = blockIdx.x * blockDim.x + threadIdx.x; i < n4; i += stride) {
        float4 v = q4[i];
        acc += (double)v.x * v.x + (double)v.y * v.y +
               (double)v.z * v.z + (double)v.w * v.w;
    }
    sdata[threadIdx.x] = acc;
    __syncthreads();
    for (int s = RTHREADS / 2; s > 0; s >>= 1) {
        if (threadIdx.x < s) sdata[threadIdx.x] += sdata[threadIdx.x + s];
        __syncthreads();
    }
    if (threadIdx.x == 0) partials[blockIdx.x] = sdata[0];
}

// ---------------------------------------------------------------------------
// Stage 2: every block redundantly reduces the 1024 partials (deterministic,
// identical result — L1-hot after the first block per CU), computes its chunk
// of 256 gaussians, stages the 3x3 outputs in LDS, and streams them with
// coalesced NON-TEMPORAL float4 stores.
// ---------------------------------------------------------------------------
__global__ __launch_bounds__(BLOCK) void gp_main(
    const float4* __restrict__ q,
    const float* __restrict__ scales,
    const float* __restrict__ opac_in,
    const double* __restrict__ partials,
    float* __restrict__ cov,
    float* __restrict__ inv_cov,
    float* __restrict__ opac_out,
    int n) {
    __shared__ union SU {
        double red[4];
        float mat[2 * CHUNK * 9];  // [0..2304) cov, [2304..4608) inv_cov
    } u;
    __shared__ float s_sc[CHUNK * 3];

    const int tid = threadIdx.x;
    const int c0 = blockIdx.x * CHUNK;
    const int count = min(CHUNK, n - c0);

    // ---- issue input loads early ----
    float4 qi = make_float4(0.f, 0.f, 0.f, 0.f);
    float op = 0.f;
    if (tid < count) {
        qi = q[c0 + tid];
        op = opac_in[c0 + tid];
    }
    // stage scales via coalesced float4 loads
    const int nsf = count * 3;
    const int nsf4 = nsf >> 2;
    const float4* sc4 = (const float4*)(scales + (size_t)c0 * 3);
    float4 sv = make_float4(0.f, 0.f, 0.f, 0.f);
    if (tid < nsf4) sv = sc4[tid];

    // ---- norm: reduce 1024 partials (deterministic, same in every block) ----
    double acc = 0.0;
#pragma unroll
    for (int k = 0; k < RBLOCKS / 256; ++k) acc += partials[tid + 256 * k];
#pragma unroll
    for (int off = 32; off > 0; off >>= 1) acc += __shfl_down(acc, off);
    if ((tid & 63) == 0) u.red[tid >> 6] = acc;

    // park scales into LDS
    if (tid < nsf4) {
        s_sc[4 * tid + 0] = sv.x;
        s_sc[4 * tid + 1] = sv.y;
        s_sc[4 * tid + 2] = sv.z;
        s_sc[4 * tid + 3] = sv.w;
    }
    {
        int r = nsf - (nsf4 << 2);
        if (tid < r) s_sc[(nsf4 << 2) + tid] =
            scales[(size_t)c0 * 3 + (nsf4 << 2) + tid];
    }
    __syncthreads();

    double tot = u.red[0] + u.red[1] + u.red[2] + u.red[3];
    const float inv_norm = (float)(1.0 / sqrt(tot));
    __syncthreads();  // all reads of u.red done before u.mat overwrites it

    // ---- compute ----
    if (tid < count) {
        float w = qi.x * inv_norm;
        float x = qi.y * inv_norm;
        float y = qi.z * inv_norm;
        float z = qi.w * inv_norm;

        float xx = x * x, yy = y * y, zz = z * z;
        float xy = x * y, xz = x * z, yz = y * z;
        float xw = x * w, yw = y * w, zw = z * w;

        float r00 = 1.f - 2.f * (yy + zz);
        float r01 = 2.f * (xy - zw);
        float r02 = 2.f * (xz + yw);
        float r10 = 2.f * (xy + zw);
        float r11 = 1.f - 2.f * (xx + zz);
        float r12 = 2.f * (yz - xw);
        float r20 = 2.f * (xz - yw);
        float r21 = 2.f * (yz + xw);
        float r22 = 1.f - 2.f * (xx + yy);

        float s0 = s_sc[3 * tid + 0];
        float s1 = s_sc[3 * tid + 1];
        float s2 = s_sc[3 * tid + 2];

        float e0 = __expf(2.f * s0), e1 = __expf(2.f * s1), e2 = __expf(2.f * s2);
        float f0 = 1.f / e0, f1 = 1.f / e1, f2 = 1.f / e2;

        float* mc = &u.mat[tid * 9];
        float* mi = &u.mat[CHUNK * 9 + tid * 9];
        {
            float a0 = r00 * e0, a1 = r01 * e1, a2 = r02 * e2;
            float b0 = r10 * e0, b1 = r11 * e1, b2 = r12 * e2;
            float g0 = r20 * e0, g1 = r21 * e1, g2 = r22 * e2;
            float m00 = a0 * r00 + a1 * r01 + a2 * r02;
            float m01 = a0 * r10 + a1 * r11 + a2 * r12;
            float m02 = a0 * r20 + a1 * r21 + a2 * r22;
            float m11 = b0 * r10 + b1 * r11 + b2 * r12;
            float m12 = b0 * r20 + b1 * r21 + b2 * r22;
            float m22 = g0 * r20 + g1 * r21 + g2 * r22;
            mc[0] = m00; mc[1] = m01; mc[2] = m02;
            mc[3] = m01; mc[4] = m11; mc[5] = m12;
            mc[6] = m02; mc[7] = m12; mc[8] = m22;
        }
        {
            float a0 = r00 * f0, a1 = r01 * f1, a2 = r02 * f2;
            float b0 = r10 * f0, b1 = r11 * f1, b2 = r12 * f2;
            float g0 = r20 * f0, g1 = r21 * f1, g2 = r22 * f2;
            float m00 = a0 * r00 + a1 * r01 + a2 * r02;
            float m01 = a0 * r10 + a1 * r11 + a2 * r12;
            float m02 = a0 * r20 + a1 * r21 + a2 * r22;
            float m11 = b0 * r10 + b1 * r11 + b2 * r12;
            float m12 = b0 * r20 + b1 * r21 + b2 * r22;
            float m22 = g0 * r20 + g1 * r21 + g2 * r22;
            mi[0] = m00; mi[1] = m01; mi[2] = m02;
            mi[3] = m01; mi[4] = m11; mi[5] = m12;
            mi[6] = m02; mi[7] = m12; mi[8] = m22;
        }
        // opacity (coalesced scalar store)
        opac_out[c0 + tid] = 1.f / (1.f + __expf(-op));
    }
    __syncthreads();

    // ---- coalesced NON-TEMPORAL float4 stores of cov / inv_cov ----
    const int nf = count * 9;
    const int nfv = nf >> 2;
    f32x4* covo = (f32x4*)(cov + (size_t)c0 * 9);
    f32x4* invo = (f32x4*)(inv_cov + (size_t)c0 * 9);
    const f32x4* mc4 = (const f32x4*)u.mat;
    const f32x4* mi4 = (const f32x4*)(u.mat + CHUNK * 9);
    for (int j = tid; j < nfv; j += BLOCK) {
        __builtin_nontemporal_store(mc4[j], covo + j);
        __builtin_nontemporal_store(mi4[j], invo + j);
    }
    for (int j = (nfv << 2) + tid; j < nf; j += BLOCK) {
        cov[(size_t)c0 * 9 + j] = u.mat[j];
        inv_cov[(size_t)c0 * 9 + j] = u.mat[CHUNK * 9 + j];
    }
}

extern "C" void kernel_launch(void* const* d_in, const int* in_sizes, int n_in,
                              void* d_out, int out_size, void* d_ws, size_t ws_size,
                              hipStream_t stream) {
    const float4* q = (const float4*)d_in[0];      // (N,4)
    const float* scales = (const float*)d_in[1];   // (N,3)
    const float* opac = (const float*)d_in[2];     // (N,1)
    int n = in_sizes[0] / 4;

    float* out = (float*)d_out;
    float* cov = out;                        // N*9
    float* inv_cov = out + (size_t)n * 9;    // N*9
    float* opac_out = out + (size_t)n * 18;  // N

    double* partials = (double*)d_ws;        // RBLOCKS doubles

    gp_reduce_sq<<<RBLOCKS, RTHREADS, 0, stream>>>(q, n, partials);

    int nblocks = (n + CHUNK - 1) / CHUNK;
    gp_main<<<nblocks, BLOCK, 0, stream>>>(
        q, scales, opac, partials, cov, inv_cov, opac_out, n);
}